// Round 2
// baseline (81.533 us; speedup 1.0000x reference)
//
#include <hip/hip_runtime.h>

// Factorized NaiveBias2d:
//   out[n, a*32+b, h, d] = sum_e bias[h,b,e]*Vc[n,e,h,d] + sum_c bias[h,a,c]*Ve[n,c,h,d]
//   bias[h,j,i] = w[h, (32 + j - i) % 63]
//   Vc[n,e,h,d] = sum_c v[n, c*32+e, h, d]   Ve[n,c,h,d] = sum_e v[n, c*32+e, h, d]
//
// Constants: BATCH=8, SEQ=1024 (32x32), HEADS=8, DIM=64 -> hd stride 512 floats.
//
// v3: stage 2 rewritten register-resident.
//   v2's inner loop was LDS-throughput-bound (~1K ds_read wave-ops/block) and
//   recomputed T1 16x. Now: each thread holds Vc/Ve columns in 64 VGPRs
//   (loaded from the L2-resident 1 MB Vc/Ve), bias comes in via SGPR
//   (wave-uniform index -> s_load), so the hot loop is pure v_fmac with a
//   scalar operand. 8 a-rows per block -> T1 redundancy 16x -> 4x.
//   LDS only for the 10 KB T1/T2 cross-wave exchange before the store.

#define S 32
#define HD4 128   // hd extent in float4 units

// ---------------- Stage 1: reductions over c (Vc) and e (Ve) ----------------
// grid 512 blocks x 128 threads (float4 per thread over hd).
// Blocks 0..255: Vc (block=n*32+e). Blocks 256..511: Ve (block=n*32+c).
// Each wave-load is 64 lanes x 16 B = 1 KiB contiguous (coalescing sweet spot).
__global__ __launch_bounds__(128) void reduce_kernel(
    const float4* __restrict__ v, float4* __restrict__ Vc,
    float4* __restrict__ Ve) {
  int block = blockIdx.x;
  int t = threadIdx.x;                  // 0..127
  bool isVc = block < 256;
  int b2 = isVc ? block : block - 256;  // n*32 + x
  int n = b2 >> 5;
  int x = b2 & 31;                      // e for Vc, c for Ve
  const float4* base = v + (size_t)n * 1024 * HD4 + t;
  float4 acc = make_float4(0.f, 0.f, 0.f, 0.f);
  if (isVc) {
#pragma unroll
    for (int c = 0; c < 32; ++c) {
      float4 r = base[(size_t)(c * S + x) * HD4];
      acc.x += r.x; acc.y += r.y; acc.z += r.z; acc.w += r.w;
    }
    Vc[(size_t)b2 * HD4 + t] = acc;
  } else {
#pragma unroll
    for (int e = 0; e < 32; ++e) {
      float4 r = base[(size_t)(x * S + e) * HD4];
      acc.x += r.x; acc.y += r.y; acc.z += r.z; acc.w += r.w;
    }
    Ve[(size_t)b2 * HD4 + t] = acc;
  }
}

// ---------------- Stage 2: fused terms + out, register-resident ----------------
// grid 256 blocks: blk = (n*8 + h)*4 + aq; aq owns a in [aq*8, aq*8+8).
// 512 threads (8 waves, 2/SIMD). Thread (wave bg, lane d):
//   regs: vc[e] = Vc[n,e,h,d], ve[c] = Ve[n,c,h,d]   (64 dword loads, L2-hot)
//   T1 rows b = kb*8+bg (4 rows): acc += s_load(wrow[32+b-e]) * vc[e]
//   T2 row  a = aq*8+bg (1 row)
//   exchange via LDS (10 KB), then 8 float4 stores/thread (4x256B segs/wave).
__global__ __launch_bounds__(512) void fused_kernel(
    const float* __restrict__ w,
    const float* __restrict__ Vc, const float* __restrict__ Ve,
    float4* __restrict__ out) {
  __shared__ float t1_s[32][64];
  __shared__ float t2_s[8][64];

  int blk = blockIdx.x;
  int aq = blk & 3;
  int nh = blk >> 2;
  int n = nh >> 3, h = nh & 7;
  int t = threadIdx.x;
  int d = t & 63;
  // force wave-uniformity so bias indices become SGPR -> s_load operands
  int bg = __builtin_amdgcn_readfirstlane(t >> 6);   // 0..7

  const float* wrow = w + h * 63;
  const float* vcb = Vc + ((size_t)(n * S) * 8 + h) * 64 + d;
  const float* veb = Ve + ((size_t)(n * S) * 8 + h) * 64 + d;

  float vc[32], ve[32];
#pragma unroll
  for (int e = 0; e < 32; ++e) {
    vc[e] = vcb[(size_t)e * 512];
    ve[e] = veb[(size_t)e * 512];
  }

  // T1 rows b = kb*8 + bg
#pragma unroll
  for (int kb = 0; kb < 4; ++kb) {
    int b = kb * 8 + bg;
    float acc = 0.f;
#pragma unroll
    for (int e = 0; e < 32; ++e) {
      int k = 32 + b - e;            // in [1,63]
      if (k >= 63) k -= 63;          // 63 -> 0
      acc += wrow[k] * vc[e];
    }
    t1_s[b][d] = acc;
  }
  // T2 row a = aq*8 + bg
  {
    int a = aq * 8 + bg;
    float acc = 0.f;
#pragma unroll
    for (int c = 0; c < 32; ++c) {
      int k = 32 + a - c;
      if (k >= 63) k -= 63;
      acc += wrow[k] * ve[c];
    }
    t2_s[bg][d] = acc;
  }
  __syncthreads();

  // 8 a-rows x 32 b-rows x 16 float4 = 4096 float4 per block, 8 per thread.
#pragma unroll
  for (int i = 0; i < 8; ++i) {
    int idx = i * 512 + t;                 // 0..4095
    int d4 = idx & 15;
    int brow = (idx >> 4) & 31;
    int al = idx >> 9;                     // 0..7
    float4 x = *(const float4*)(&t1_s[brow][d4 * 4]);
    float4 y = *(const float4*)(&t2_s[al][d4 * 4]);
    out[((size_t)(n * 1024 + (aq * 8 + al) * S + brow) * 8 + h) * 16 + d4] =
        make_float4(x.x + y.x, x.y + y.y, x.z + y.z, x.w + y.w);
  }
}

extern "C" void kernel_launch(void* const* d_in, const int* in_sizes, int n_in,
                              void* d_out, int out_size, void* d_ws, size_t ws_size,
                              hipStream_t stream) {
  const float* v = (const float*)d_in[0];   // (8,1024,8,64) fp32
  const float* w = (const float*)d_in[1];   // (1,8,63)      fp32
  float* out = (float*)d_out;               // (8,1024,8,64) fp32
  float* ws  = (float*)d_ws;

  float* Vc = ws;                 // 131072 floats
  float* Ve = ws + 131072;        // 131072   (1 MB total)

  reduce_kernel<<<512, 128, 0, stream>>>((const float4*)v, (float4*)Vc,
                                         (float4*)Ve);
  fused_kernel<<<256, 512, 0, stream>>>(w, Vc, Ve, (float4*)out);
}

// Round 3
// 72.123 us; speedup vs baseline: 1.1305x; 1.1305x over previous
//
#include <hip/hip_runtime.h>

// Factorized NaiveBias2d:
//   out[n, a*32+b, h, d] = sum_e bias[h,b,e]*Vc[n,e,h,d] + sum_c bias[h,a,c]*Ve[n,c,h,d]
//   bias[h,j,i] = w[h, (32 + j - i) % 63]
//   Vc[n,e,h,d] = sum_c v[n, c*32+e, h, d]   Ve[n,c,h,d] = sum_e v[n, c*32+e, h, d]
//
// Constants: BATCH=8, SEQ=1024 (32x32), HEADS=8, DIM=64.
//
// v4: SINGLE kernel, blocks split along d.
//   block = (dq-major | n | h), dq = d-eighth (8 of 64 d). Each block:
//     load v[n, :, h, d8] (32 KB) -> LDS   [one global read of v total]
//     reduce -> Vc[32][8], Ve[32][8] in LDS
//     matmul -> T1[32][8], T2[32][8] (bias via LDS, rotation-indexed)
//     store out[n, :, h, d8] (32 KB) directly.
//   Min traffic 16 MB in + 16 MB out, one launch, no workspace.
//   dq-major block order: all 8 dq-blocks of one (n,h) hit the SAME XCD
//   (blk & 7 == nh & 7), so each 256B line is fetched into one L2 once.
//   Rotations e'=(e+x)&31 keep stride-256 LDS reads at <=2-way (free).

#define S 32

__global__ __launch_bounds__(256) void fused_all(
    const float4* __restrict__ v4, const float* __restrict__ w,
    float4* __restrict__ out4) {
  __shared__ float vs_s[1024][8];     // 32 KB: v[n, l, h, d0:d0+8]
  __shared__ float bias_s[32][33];    // padded
  __shared__ float vc_s[32][8];
  __shared__ float ve_s[32][8];
  __shared__ float t1_s[32][8];
  __shared__ float t2_s[32][8];

  int blk = blockIdx.x;
  int dq = blk >> 6;                  // 0..7  (d0 = dq*8)
  int nh = blk & 63;
  int n = nh >> 3, h = nh & 7;
  int t = threadIdx.x;                // 0..255

  // ---- stage bias (4 entries/thread) ----
#pragma unroll
  for (int i = 0; i < 4; ++i) {
    int idx = i * 256 + t;            // 0..1023
    int b = idx >> 5, e = idx & 31;
    bias_s[b][e] = w[h * 63 + (32 + b - e) % 63];
  }

  // ---- load v slice: 1024 rows x 32 B (2 float4 per row) ----
  // float4 index of (n,l,h,d4): ((n*1024+l)*8+h)*16 + d4 ; d4 = dq*2 + k
  const float4* vbase = v4 + ((size_t)(n * 1024) * 8 + h) * 16 + dq * 2;
#pragma unroll
  for (int i = 0; i < 8; ++i) {
    int idx = i * 256 + t;            // 0..2047
    int l = idx >> 1, k = idx & 1;
    *(float4*)(&vs_s[l][k * 4]) = vbase[(size_t)l * 128 + k];
  }
  __syncthreads();

  // ---- reductions ----
  // thread t -> (x = t>>3, d = t&7)
  {
    int x = t >> 3, d = t & 7;
    float accc = 0.f, acce = 0.f;
#pragma unroll
    for (int c = 0; c < 32; ++c)      // Vc[x][d]: word = c*256 + t (bank-perfect)
      accc += vs_s[c * S + x][d];
#pragma unroll
    for (int e = 0; e < 32; ++e) {    // Ve[x][d]: rotate to break stride-256 alias
      int e2 = (e + x) & 31;
      acce += vs_s[x * S + e2][d];
    }
    vc_s[x][d] = accc;
    ve_s[x][d] = acce;
  }
  __syncthreads();

  // ---- T1/T2: 32x32 bias matmuls (one element of each per thread) ----
  {
    int b = t >> 3, d = t & 7;        // b doubles as a-row for T2
    float a1 = 0.f, a2 = 0.f;
#pragma unroll
    for (int e = 0; e < 32; ++e) {
      int e2 = (e + b) & 31;
      float bw = bias_s[b][e2];
      a1 += bw * vc_s[e2][d];
      a2 += bw * ve_s[e2][d];
    }
    t1_s[b][d] = a1;
    t2_s[b][d] = a2;
  }
  __syncthreads();

  // ---- store: out[n, a*32+b, h, d0:d0+8] = T1[b] + T2[a] ----
  float4* obase = out4 + ((size_t)(n * 1024) * 8 + h) * 16 + dq * 2;
#pragma unroll
  for (int i = 0; i < 8; ++i) {
    int idx = i * 256 + t;            // 0..2047
    int k = idx & 1;
    int j = idx >> 1;                 // 0..1023
    int b = j & 31, a = j >> 5;
    float4 x = *(const float4*)(&t1_s[b][k * 4]);
    float4 y = *(const float4*)(&t2_s[a][k * 4]);
    obase[(size_t)j * 128 + k] =
        make_float4(x.x + y.x, x.y + y.y, x.z + y.z, x.w + y.w);
  }
}

extern "C" void kernel_launch(void* const* d_in, const int* in_sizes, int n_in,
                              void* d_out, int out_size, void* d_ws, size_t ws_size,
                              hipStream_t stream) {
  const float* v = (const float*)d_in[0];   // (8,1024,8,64) fp32
  const float* w = (const float*)d_in[1];   // (1,8,63)      fp32
  float* out = (float*)d_out;               // (8,1024,8,64) fp32
  (void)d_ws; (void)ws_size;

  fused_all<<<512, 256, 0, stream>>>((const float4*)v, w, (float4*)out);
}

// Round 4
// 72.053 us; speedup vs baseline: 1.1316x; 1.0010x over previous
//
#include <hip/hip_runtime.h>

// Factorized NaiveBias2d:
//   out[n, a*32+b, h, d] = sum_e bias[h,b,e]*Vc[n,e,h,d] + sum_c bias[h,a,c]*Ve[n,c,h,d]
//   bias[h,j,i] = w[h, (32 + j - i) % 63]
//   Vc[n,e,h,d] = sum_c v[n, c*32+e, h, d]   Ve[n,c,h,d] = sum_e v[n, c*32+e, h, d]
//
// Constants: BATCH=8, SEQ=1024 (32x32), HEADS=8, DIM=64.
//
// v5 = v4 (single kernel, d-eighth split) + LDS-pipe cuts:
//   - Vc reduction done in REGISTERS during load (each thread's 8 rows share
//     e=(t>>1)&31), finished via a 4 KB partial exchange: 32 ds_read -> 4.
//   - t1_s read hoisted out of the store loop (loop-invariant b); t2_s reads
//     are wave-uniform broadcasts. 16 conflicted reads -> 1. t1 stride 12
//     words (16B-aligned) cuts the remaining alias 8-way -> 4-way.
//   - w loads issued before v loads (bias staging doesn't drain v queue).
//   dq-major grid: all 8 dq-blocks of one (n,h) land on the same XCD
//   (blk&7 == nh&7) so each 128B line is fetched once / assembled once.

#define S 32

__global__ __launch_bounds__(256) void fused_all(
    const float4* __restrict__ v4, const float* __restrict__ w,
    float4* __restrict__ out4) {
  __shared__ float vs_s[1024][8];     // 32 KB: v[n, l, h, d0:d0+8]
  __shared__ float vcp_s[1024];       // 4 KB: Vc partials [q][e][8d]
  __shared__ float bias_s[32][33];    // padded
  __shared__ float vc_s[32][8];
  __shared__ float ve_s[32][8];
  __shared__ float t1_s[32][12];      // stride 12 words: 16B-aligned, 4-way max
  __shared__ float t2_s[32][8];

  int blk = blockIdx.x;
  int dq = blk >> 6;                  // 0..7  (d0 = dq*8)
  int nh = blk & 63;
  int n = nh >> 3, h = nh & 7;
  int t = threadIdx.x;                // 0..255

  // ---- bias weights first (2 KB, L1/L2-hot) ----
  float wreg[4];
#pragma unroll
  for (int i = 0; i < 4; ++i) {
    int idx = i * 256 + t;            // 0..1023
    int b = idx >> 5, e = idx & 31;
    wreg[i] = w[h * 63 + (32 + b - e) % 63];
  }

  // ---- load v slice: 1024 rows x 32 B; thread t row l=128i+(t>>1), half k=t&1
  const float4* vbase = v4 + ((size_t)(n * 1024) * 8 + h) * 16 + dq * 2;
  float4 r[8];
#pragma unroll
  for (int i = 0; i < 8; ++i) {
    int l = i * 128 + (t >> 1);
    r[i] = vbase[(size_t)l * 128 + (t & 1)];
  }

#pragma unroll
  for (int i = 0; i < 4; ++i) {
    int idx = i * 256 + t;
    bias_s[idx >> 5][idx & 31] = wreg[i];
  }

  // vs_s write: byte offset t*16 per i-plane (contiguous b128, conflict-free)
#pragma unroll
  for (int i = 0; i < 8; ++i) {
    int l = i * 128 + (t >> 1);
    *(float4*)(&vs_s[l][(t & 1) * 4]) = r[i];
  }
  // Vc partial: all 8 rows share e=(t>>1)&31; c spans {q,q+4,..,q+28}, q=t>>6.
  {
    float4 p = r[0];
#pragma unroll
    for (int i = 1; i < 8; ++i) {
      p.x += r[i].x; p.y += r[i].y; p.z += r[i].z; p.w += r[i].w;
    }
    *(float4*)(&vcp_s[4 * t]) = p;    // flat index q*256 + e*8 + k*4
  }
  __syncthreads();

  // ---- finish reductions ----
  {
    int x = t >> 3, d = t & 7;
    // Vc: sum 4 partials (contiguous words per q-plane -> conflict-free)
    float accc = vcp_s[t] + vcp_s[256 + t] + vcp_s[512 + t] + vcp_s[768 + t];
    vc_s[x][d] = accc;
    // Ve: rotate to break stride-256 alias (<=2-way, free)
    float acce = 0.f;
#pragma unroll
    for (int e = 0; e < 32; ++e) {
      int e2 = (e + x) & 31;
      acce += vs_s[x * S + e2][d];
    }
    ve_s[x][d] = acce;
  }
  __syncthreads();

  // ---- T1/T2: 32x32 bias matmuls (one element of each per thread) ----
  {
    int b = t >> 3, d = t & 7;        // b doubles as a-row for T2
    float a1 = 0.f, a2 = 0.f;
#pragma unroll
    for (int e = 0; e < 32; ++e) {
      int e2 = (e + b) & 31;
      float bw = bias_s[b][e2];
      a1 += bw * vc_s[e2][d];
      a2 += bw * ve_s[e2][d];
    }
    t1_s[b][d] = a1;
    t2_s[b][d] = a2;
  }
  __syncthreads();

  // ---- store: out[n, a*32+b, h, d0:d0+8] = T1[b] + T2[a] ----
  // m=t>>1: b=m&31 loop-invariant -> hoist t1 read; t2 read is wave-uniform.
  float4* obase = out4 + ((size_t)(n * 1024) * 8 + h) * 16 + dq * 2;
  {
    int m = t >> 1, k = t & 1;
    int b = m & 31, mq = m >> 5;
    float4 x = *(const float4*)(&t1_s[b][k * 4]);
#pragma unroll
    for (int i = 0; i < 8; ++i) {
      int a = i * 4 + mq;
      int j = a * S + b;              // == i*128 + m
      float4 y = *(const float4*)(&t2_s[a][k * 4]);
      obase[(size_t)j * 128 + k] =
          make_float4(x.x + y.x, x.y + y.y, x.z + y.z, x.w + y.w);
    }
  }
}

extern "C" void kernel_launch(void* const* d_in, const int* in_sizes, int n_in,
                              void* d_out, int out_size, void* d_ws, size_t ws_size,
                              hipStream_t stream) {
  const float* v = (const float*)d_in[0];   // (8,1024,8,64) fp32
  const float* w = (const float*)d_in[1];   // (1,8,63)      fp32
  float* out = (float*)d_out;               // (8,1024,8,64) fp32
  (void)d_ws; (void)ws_size;

  fused_all<<<512, 256, 0, stream>>>((const float4*)v, w, (float4*)out);
}